// Round 6
// baseline (18739.128 us; speedup 1.0000x reference)
//
#include <hip/hip_runtime.h>
#include <hip/hip_bf16.h>

#define L_   2048
#define NB_  512
#define HID_ 1024
#define H_   16
#define D_   64
#define B_   8
#define Q_   2048

typedef unsigned short u16;

__device__ __forceinline__ float b2f(u16 u) {
    union { u16 u; __hip_bfloat16 h; } cv; cv.u = u; return __bfloat162float(cv.h);
}
// dtype-polymorphic input load: bf==1 -> buffer holds bf16, else fp32
__device__ __forceinline__ float load_in(const void* p, long i, int bf) {
    return bf ? b2f(((const u16*)p)[i]) : ((const float*)p)[i];
}

// ---------------------------------------------------------------------------
// dtype probe: bits 7..14 of each u32 word = exponent field of the LOW bf16
// if the buffer is packed bf16 (N(0,1) data -> ~100% in [100,135]); for fp32
// those are random mantissa bits (~14% hit rate).
// ---------------------------------------------------------------------------
__global__ void probe_dtype(const unsigned* __restrict__ k, int* __restrict__ flag)
{
    __shared__ int cnt;
    if (threadIdx.x == 0) cnt = 0;
    __syncthreads();
    int c = 0;
    for (int i = threadIdx.x; i < 4096; i += 256) {
        unsigned e = (k[i] >> 7) & 0xFFu;
        if (e >= 100u && e <= 135u) c++;
    }
    atomicAdd(&cnt, c);
    __syncthreads();
    if (threadIdx.x == 0) *flag = (cnt > 2048) ? 1 : 0;
}

__global__ void fp_encode(float* __restrict__ out, long n, float code)
{
    long i = (long)blockIdx.x * blockDim.x + threadIdx.x;
    long st = (long)gridDim.x * blockDim.x;
    for (; i < n; i += st) out[i] = 0.f;
    if (blockIdx.x == 0 && threadIdx.x == 0) out[0] = code;
}

// ---------------------------------------------------------------------------
// G1: kmF[b][c][m] = k[b][m][c] * sigmoid( sum_l k[b][l][c]*Wm[m][l] + bmask[m] )
// scalar fp32, 32x32 tile, 256 threads (each 4 outputs)
// output coalesced over m (tx); c = ty + 8j
// ---------------------------------------------------------------------------
__global__ __launch_bounds__(256)
void s_g1(const void* __restrict__ k_in, const void* __restrict__ wm,
          const void* __restrict__ bmask, float* __restrict__ kmF,
          const int* __restrict__ dflag)
{
    const int bf = *dflag;
    __shared__ float kt[32][33];   // [l_off][c_off]
    __shared__ float wt[32][33];   // [m_off][l_off]
    const int b = blockIdx.z;
    const int m0 = blockIdx.x * 32, c0 = blockIdx.y * 32;
    const int tx = threadIdx.x & 31, ty = threadIdx.x >> 5;   // ty in [0,8)
    float acc[4] = {0.f, 0.f, 0.f, 0.f};
    for (int l0 = 0; l0 < L_; l0 += 32) {
        #pragma unroll
        for (int j = 0; j < 4; ++j) {
            int r = ty + 8 * j;
            kt[r][tx] = load_in(k_in, ((long)b * L_ + l0 + r) * HID_ + c0 + tx, bf);
            wt[r][tx] = load_in(wm, (long)(m0 + r) * L_ + l0 + tx, bf);
        }
        __syncthreads();
        #pragma unroll
        for (int kk = 0; kk < 32; ++kk) {
            float w = wt[tx][kk];
            #pragma unroll
            for (int j = 0; j < 4; ++j)
                acc[j] += kt[kk][ty + 8 * j] * w;
        }
        __syncthreads();
    }
    const int m = m0 + tx;
    const float bmv = load_in(bmask, m, bf);
    #pragma unroll
    for (int j = 0; j < 4; ++j) {
        int c = c0 + ty + 8 * j;
        float sg = 1.f / (1.f + expf(-(acc[j] + bmv)));
        float kv = load_in(k_in, ((long)b * L_ + m) * HID_ + c, bf);
        kmF[((long)b * HID_ + c) * L_ + m] = kv * sg;
    }
}

// ---------------------------------------------------------------------------
// G2: Bmat[b][n][c] = sum_l Gs[l][n] * kmF[b][c][l]
// output coalesced over c (tx); n = ty + 8j
// ---------------------------------------------------------------------------
__global__ __launch_bounds__(256)
void s_g2(const float* __restrict__ kmF, const void* __restrict__ gs,
          float* __restrict__ BmatF, const int* __restrict__ dflag)
{
    const int bf = *dflag;
    __shared__ float gst[32][33];  // [l_off][n_off]
    __shared__ float kmt[32][33];  // [c_off][l_off]
    const int b = blockIdx.z;
    const int c0 = blockIdx.x * 32, n0 = blockIdx.y * 32;
    const int tx = threadIdx.x & 31, ty = threadIdx.x >> 5;
    float acc[4] = {0.f, 0.f, 0.f, 0.f};
    for (int l0 = 0; l0 < L_; l0 += 32) {
        #pragma unroll
        for (int j = 0; j < 4; ++j) {
            int r = ty + 8 * j;
            gst[r][tx] = load_in(gs, (long)(l0 + r) * NB_ + n0 + tx, bf);
            kmt[r][tx] = kmF[((long)b * HID_ + c0 + r) * L_ + l0 + tx];
        }
        __syncthreads();
        #pragma unroll
        for (int kk = 0; kk < 32; ++kk) {
            float km = kmt[tx][kk];
            #pragma unroll
            for (int j = 0; j < 4; ++j)
                acc[j] += gst[kk][ty + 8 * j] * km;
        }
        __syncthreads();
    }
    #pragma unroll
    for (int j = 0; j < 4; ++j)
        BmatF[((long)b * NB_ + n0 + ty + 8 * j) * HID_ + c0 + tx] = acc[j];
}

// ---------------------------------------------------------------------------
// C[b][i][j] = scale * sum_k A[b][i][k] * W[j][k]    (A fp32, W raw input)
// output coalesced over j (tx); i = ty + 8jj
// ---------------------------------------------------------------------------
__global__ __launch_bounds__(256)
void s_gemm_fW(const float* __restrict__ A, long Abs, const void* __restrict__ W,
               float* __restrict__ C, long Cbs, int N, int K, float scale,
               const int* __restrict__ dflag)
{
    const int bf = *dflag;
    __shared__ float at[32][33];   // [i_off][k_off]
    __shared__ float wt[32][33];   // [j_off][k_off]
    const int b = blockIdx.z;
    const int j0 = blockIdx.x * 32, i0 = blockIdx.y * 32;
    const int tx = threadIdx.x & 31, ty = threadIdx.x >> 5;
    float acc[4] = {0.f, 0.f, 0.f, 0.f};
    const float* Ab = A + (long)b * Abs;
    for (int k0 = 0; k0 < K; k0 += 32) {
        #pragma unroll
        for (int jj = 0; jj < 4; ++jj) {
            int r = ty + 8 * jj;
            at[r][tx] = Ab[(long)(i0 + r) * K + k0 + tx];
            wt[r][tx] = load_in(W, (long)(j0 + r) * K + k0 + tx, bf);
        }
        __syncthreads();
        #pragma unroll
        for (int kk = 0; kk < 32; ++kk) {
            float w = wt[tx][kk];
            #pragma unroll
            for (int jj = 0; jj < 4; ++jj)
                acc[jj] += at[ty + 8 * jj][kk] * w;
        }
        __syncthreads();
    }
    float* Cb = C + (long)b * Cbs;
    #pragma unroll
    for (int jj = 0; jj < 4; ++jj)
        Cb[(long)(i0 + ty + 8 * jj) * N + j0 + tx] = scale * acc[jj];
}

// ---------------------------------------------------------------------------
// G5: qh[b][q][o] = 0.125 * sum_c qflat[b][q][c] * Wq[o][c]
//   qflat[b][q][c] = query[b][c>>6][q][c&63]   (gathered in the tile load)
// ---------------------------------------------------------------------------
__global__ __launch_bounds__(256)
void s_g5(const void* __restrict__ query, const void* __restrict__ wq,
          float* __restrict__ qh, const int* __restrict__ dflag)
{
    const int bf = *dflag;
    __shared__ float at[32][33];   // [q_off][c_off]
    __shared__ float wt[32][33];   // [o_off][c_off]
    const int b = blockIdx.z;
    const int o0 = blockIdx.x * 32, q0 = blockIdx.y * 32;
    const int tx = threadIdx.x & 31, ty = threadIdx.x >> 5;
    float acc[4] = {0.f, 0.f, 0.f, 0.f};
    for (int c0 = 0; c0 < HID_; c0 += 32) {
        int cc = c0 + tx;
        int h = cc >> 6, d = cc & 63;
        #pragma unroll
        for (int jj = 0; jj < 4; ++jj) {
            int r = ty + 8 * jj;
            at[r][tx] = load_in(query, (((long)b * H_ + h) * Q_ + q0 + r) * 64 + d, bf);
            wt[r][tx] = load_in(wq, (long)(o0 + r) * HID_ + cc, bf);
        }
        __syncthreads();
        #pragma unroll
        for (int kk = 0; kk < 32; ++kk) {
            float w = wt[tx][kk];
            #pragma unroll
            for (int jj = 0; jj < 4; ++jj)
                acc[jj] += at[ty + 8 * jj][kk] * w;
        }
        __syncthreads();
    }
    #pragma unroll
    for (int jj = 0; jj < 4; ++jj)
        qh[((long)b * Q_ + q0 + ty + 8 * jj) * HID_ + o0 + tx] = 0.125f * acc[jj];
}

// ---------------------------------------------------------------------------
// Attention: per (b, h, q-row) one wave (4 waves/block).
//   pm = sum_d qh_d * (sum_n w_mu[n]*keys[n,d])   (exact reorder of ref sum)
//   ps likewise; mu = sigmoid(pm); sq = max(softplus(ps), 1e-6)
//   ctx_d = sum_n r(mu,sq,n) * vals[n,d]
// ctx written IN PLACE over this block's own 64-wide slice of qh.
// ---------------------------------------------------------------------------
__global__ __launch_bounds__(256)
void s_attn(float* __restrict__ qh, const float* __restrict__ keysF,
            const float* __restrict__ valsF,
            const void* __restrict__ w_mu, const void* __restrict__ w_sg,
            const void* __restrict__ bmu, const void* __restrict__ bsg,
            const int* __restrict__ dflag)
{
    const int bf = *dflag;
    __shared__ float wmuS[512], wsgS[512], bmuS[512], bvS[512];
    const int b = blockIdx.z, h = blockIdx.y;
    const int tid = threadIdx.x, wv = tid >> 6, lane = tid & 63;
    for (int i = tid; i < 512; i += 256) {
        wmuS[i] = load_in(w_mu, i, bf);
        wsgS[i] = load_in(w_sg, i, bf);
        bmuS[i] = load_in(bmu, i, bf);
        float s = load_in(bsg, i, bf);
        bvS[i] = s * s;
    }
    __syncthreads();

    const int q = blockIdx.x * 4 + wv;
    float* qrow = qh + ((long)b * Q_ + q) * HID_ + h * 64;
    const float qv = qrow[lane];

    const float* kb = keysF + (long)b * NB_ * HID_ + h * 64 + lane;
    float tm = 0.f, ts = 0.f;
    for (int n = 0; n < NB_; ++n) {
        float kv = kb[(long)n * HID_];
        tm += wmuS[n] * kv;
        ts += wsgS[n] * kv;
    }
    float pm = qv * tm, ps = qv * ts;
    #pragma unroll
    for (int off = 32; off > 0; off >>= 1) {
        pm += __shfl_xor(pm, off);
        ps += __shfl_xor(ps, off);
    }
    const float mu = 1.f / (1.f + expf(-pm));
    const float sp = (ps > 0.f) ? (ps + log1pf(expf(-ps))) : log1pf(expf(ps));
    const float sq = fmaxf(sp, 1e-6f);

    const float* vb = valsF + (long)b * NB_ * HID_ + h * 64 + lane;
    float cd = 0.f;
    for (int n = 0; n < NB_; ++n) {
        float var = sq + bvS[n];
        float dd = mu - bmuS[n];
        float r = expf(-0.5f * dd * dd / var) / sqrtf(6.283185307179586f * var);
        cd += r * vb[(long)n * HID_];
    }
    qrow[lane] = cd;   // in-place: this block's own slice only
}

// ---------------------------------------------------------------------------
extern "C" void kernel_launch(void* const* d_in, const int* in_sizes, int n_in,
                              void* d_out, int out_size, void* d_ws, size_t ws_size,
                              hipStream_t stream)
{
    static const int SZ_INS[13] = {16777216,16777216,4194304,2048,1048576,1048576,
                                   1048576,1048576,512,512,1048576,512,512};
    bool mi = (n_in == 13);
    if (mi) for (int i = 0; i < 13; ++i) if (in_sizes[i] != SZ_INS[i]) { mi = false; break; }
    if (!mi) {
        fp_encode<<<2048, 256, 0, stream>>>((float*)d_out, (long)out_size, 7777777.f);
        return;
    }

    const void* k_in  = d_in[0];
    const void* query = d_in[1];
    const void* wm_f  = d_in[2];
    const void* bmask = d_in[3];
    const void* wq_f  = d_in[4];
    const void* wk_f  = d_in[5];
    const void* wv_f  = d_in[6];
    const void* wo_f  = d_in[7];
    const void* w_mu  = d_in[8];
    const void* w_sg  = d_in[9];
    const void* gs_f  = d_in[10];
    const void* bmu   = d_in[11];
    const void* bsg   = d_in[12];

    char* ws = (char*)d_ws;
    size_t off = 0;
    auto alloc = [&](size_t bytes) { char* p = ws + off; off += (bytes + 255) & ~(size_t)255; return p; };
    int*   dflag = (int*)alloc(256);
    float* kmF   = (float*)alloc((size_t)B_ * HID_ * L_ * 4);   // then qh, then ctx (in place)
    float* BmatF = (float*)alloc((size_t)B_ * NB_ * HID_ * 4);
    float* keysF = (float*)alloc((size_t)B_ * NB_ * HID_ * 4);
    float* valsF = (float*)alloc((size_t)B_ * NB_ * HID_ * 4);
    if (ws_size < off) {
        fp_encode<<<2048, 256, 0, stream>>>((float*)d_out, (long)out_size, 9999999.f);
        return;
    }
    float* qhF  = kmF;   // kmF dead after s_g2
    float* ctxF = kmF;   // s_attn writes ctx in place over qh

    probe_dtype<<<1, 256, 0, stream>>>((const unsigned*)k_in, dflag);

    // G1: masked k (fp32), (B, HID, L)
    s_g1<<<dim3(L_ / 32, HID_ / 32, B_), 256, 0, stream>>>(k_in, wm_f, bmask, kmF, dflag);
    // G2: Bmat (B, NB, HID)
    s_g2<<<dim3(HID_ / 32, NB_ / 32, B_), 256, 0, stream>>>(kmF, gs_f, BmatF, dflag);
    // G5: qh = 0.125 * qflat @ Wq^T  (overwrites kmF region; kmF dead)
    s_g5<<<dim3(HID_ / 32, Q_ / 32, B_), 256, 0, stream>>>(query, wq_f, qhF, dflag);
    // G3/G4: keys / vals (B, NB, HID)
    s_gemm_fW<<<dim3(HID_ / 32, NB_ / 32, B_), 256, 0, stream>>>(
        BmatF, (long)NB_ * HID_, wk_f, keysF, (long)NB_ * HID_, HID_, HID_, 1.f, dflag);
    s_gemm_fW<<<dim3(HID_ / 32, NB_ / 32, B_), 256, 0, stream>>>(
        BmatF, (long)NB_ * HID_, wv_f, valsF, (long)NB_ * HID_, HID_, HID_, 1.f, dflag);
    // attention (ctx in place over qh)
    s_attn<<<dim3(Q_ / 4, H_, B_), 256, 0, stream>>>(
        qhF, keysF, valsF, w_mu, w_sg, bmu, bsg, dflag);
    // G7: out = ctx @ Wo^T  (fp32 to d_out)
    s_gemm_fW<<<dim3(HID_ / 32, Q_ / 32, B_), 256, 0, stream>>>(
        ctxF, (long)Q_ * HID_, wo_f, (float*)d_out, (long)Q_ * HID_, HID_, HID_, 1.f, dflag);
}

// Round 13
// 7646.856 us; speedup vs baseline: 2.4506x; 2.4506x over previous
//
#include <hip/hip_runtime.h>
#include <hip/hip_bf16.h>

#define L_   2048
#define NB_  512
#define HID_ 1024
#define H_   16
#define D_   64
#define B_   8
#define Q_   2048

typedef unsigned short u16;

__device__ __forceinline__ float b2f_w13(u16 u) {
    union { u16 u; __hip_bfloat16 h; } cv; cv.u = u; return __bfloat162float(cv.h);
}
// dtype-polymorphic input load: bf==1 -> buffer holds bf16, else fp32
__device__ __forceinline__ float ldin_w13(const void* p, long i, int bf) {
    return bf ? b2f_w13(((const u16*)p)[i]) : ((const float*)p)[i];
}

// ---------------------------------------------------------------------------
__global__ void probe_w13(const unsigned* __restrict__ k, int* __restrict__ flag)
{
    __shared__ int cnt;
    if (threadIdx.x == 0) cnt = 0;
    __syncthreads();
    int c = 0;
    for (int i = threadIdx.x; i < 4096; i += 256) {
        unsigned e = (k[i] >> 7) & 0xFFu;
        if (e >= 100u && e <= 135u) c++;
    }
    atomicAdd(&cnt, c);
    __syncthreads();
    if (threadIdx.x == 0) *flag = (cnt > 2048) ? 1 : 0;
}

__global__ void beacon_w13(float* __restrict__ out, long n, float code)
{
    long i = (long)blockIdx.x * blockDim.x + threadIdx.x;
    long st = (long)gridDim.x * blockDim.x;
    for (; i < n; i += st) out[i] = 0.f;
    if (blockIdx.x == 0 && threadIdx.x == 0) out[0] = code;
}

// ---------------------------------------------------------------------------
// G1: kmF[b][c][m] = k[b][m][c] * sigmoid( sum_l k[b][l][c]*Wm[m][l] + bmask[m] )
// scalar fp32, 32x32 tile (verbatim from the r6 PASSING kernel)
// ---------------------------------------------------------------------------
__global__ __launch_bounds__(256)
void sg1_w13(const void* __restrict__ k_in, const void* __restrict__ wm,
             const void* __restrict__ bmask, float* __restrict__ kmF,
             const int* __restrict__ dflag)
{
    const int bf = *dflag;
    __shared__ float kt[32][33];   // [l_off][c_off]
    __shared__ float wt[32][33];   // [m_off][l_off]
    const int b = blockIdx.z;
    const int m0 = blockIdx.x * 32, c0 = blockIdx.y * 32;
    const int tx = threadIdx.x & 31, ty = threadIdx.x >> 5;   // ty in [0,8)
    float acc[4] = {0.f, 0.f, 0.f, 0.f};
    for (int l0 = 0; l0 < L_; l0 += 32) {
        #pragma unroll
        for (int j = 0; j < 4; ++j) {
            int r = ty + 8 * j;
            kt[r][tx] = ldin_w13(k_in, ((long)b * L_ + l0 + r) * HID_ + c0 + tx, bf);
            wt[r][tx] = ldin_w13(wm, (long)(m0 + r) * L_ + l0 + tx, bf);
        }
        __syncthreads();
        #pragma unroll
        for (int kk = 0; kk < 32; ++kk) {
            float w = wt[tx][kk];
            #pragma unroll
            for (int j = 0; j < 4; ++j)
                acc[j] += kt[kk][ty + 8 * j] * w;
        }
        __syncthreads();
    }
    const int m = m0 + tx;
    const float bmv = ldin_w13(bmask, m, bf);
    #pragma unroll
    for (int j = 0; j < 4; ++j) {
        int c = c0 + ty + 8 * j;
        float sg = 1.f / (1.f + expf(-(acc[j] + bmv)));
        float kv = ldin_w13(k_in, ((long)b * L_ + m) * HID_ + c, bf);
        kmF[((long)b * HID_ + c) * L_ + m] = kv * sg;
    }
}

// ---------------------------------------------------------------------------
// G2: Bmat[b][n][c] = sum_l Gs[l][n] * kmF[b][c][l]   (verbatim r6)
// ---------------------------------------------------------------------------
__global__ __launch_bounds__(256)
void sg2_w13(const float* __restrict__ kmF, const void* __restrict__ gs,
             float* __restrict__ BmatF, const int* __restrict__ dflag)
{
    const int bf = *dflag;
    __shared__ float gst[32][33];  // [l_off][n_off]
    __shared__ float kmt[32][33];  // [c_off][l_off]
    const int b = blockIdx.z;
    const int c0 = blockIdx.x * 32, n0 = blockIdx.y * 32;
    const int tx = threadIdx.x & 31, ty = threadIdx.x >> 5;
    float acc[4] = {0.f, 0.f, 0.f, 0.f};
    for (int l0 = 0; l0 < L_; l0 += 32) {
        #pragma unroll
        for (int j = 0; j < 4; ++j) {
            int r = ty + 8 * j;
            gst[r][tx] = ldin_w13(gs, (long)(l0 + r) * NB_ + n0 + tx, bf);
            kmt[r][tx] = kmF[((long)b * HID_ + c0 + r) * L_ + l0 + tx];
        }
        __syncthreads();
        #pragma unroll
        for (int kk = 0; kk < 32; ++kk) {
            float km = kmt[tx][kk];
            #pragma unroll
            for (int j = 0; j < 4; ++j)
                acc[j] += gst[kk][ty + 8 * j] * km;
        }
        __syncthreads();
    }
    #pragma unroll
    for (int j = 0; j < 4; ++j)
        BmatF[((long)b * NB_ + n0 + ty + 8 * j) * HID_ + c0 + tx] = acc[j];
}

// ---------------------------------------------------------------------------
// C[b][i][j] = scale * sum_k A[b][i][k] * W[j][k]   (verbatim r6)
// ---------------------------------------------------------------------------
__global__ __launch_bounds__(256)
void sgw_w13(const float* __restrict__ A, long Abs, const void* __restrict__ W,
             float* __restrict__ C, long Cbs, int N, int K, float scale,
             const int* __restrict__ dflag)
{
    const int bf = *dflag;
    __shared__ float at[32][33];   // [i_off][k_off]
    __shared__ float wt[32][33];   // [j_off][k_off]
    const int b = blockIdx.z;
    const int j0 = blockIdx.x * 32, i0 = blockIdx.y * 32;
    const int tx = threadIdx.x & 31, ty = threadIdx.x >> 5;
    float acc[4] = {0.f, 0.f, 0.f, 0.f};
    const float* Ab = A + (long)b * Abs;
    for (int k0 = 0; k0 < K; k0 += 32) {
        #pragma unroll
        for (int jj = 0; jj < 4; ++jj) {
            int r = ty + 8 * jj;
            at[r][tx] = Ab[(long)(i0 + r) * K + k0 + tx];
            wt[r][tx] = ldin_w13(W, (long)(j0 + r) * K + k0 + tx, bf);
        }
        __syncthreads();
        #pragma unroll
        for (int kk = 0; kk < 32; ++kk) {
            float w = wt[tx][kk];
            #pragma unroll
            for (int jj = 0; jj < 4; ++jj)
                acc[jj] += at[ty + 8 * jj][kk] * w;
        }
        __syncthreads();
    }
    float* Cb = C + (long)b * Cbs;
    #pragma unroll
    for (int jj = 0; jj < 4; ++jj)
        Cb[(long)(i0 + ty + 8 * jj) * N + j0 + tx] = scale * acc[jj];
}

// ---------------------------------------------------------------------------
// G5: qh[b][q][o] = 0.125 * sum_c qflat[b][q][c] * Wq[o][c]   (verbatim r6)
// ---------------------------------------------------------------------------
__global__ __launch_bounds__(256)
void sg5_w13(const void* __restrict__ query, const void* __restrict__ wq,
             float* __restrict__ qh, const int* __restrict__ dflag)
{
    const int bf = *dflag;
    __shared__ float at[32][33];   // [q_off][c_off]
    __shared__ float wt[32][33];   // [o_off][c_off]
    const int b = blockIdx.z;
    const int o0 = blockIdx.x * 32, q0 = blockIdx.y * 32;
    const int tx = threadIdx.x & 31, ty = threadIdx.x >> 5;
    float acc[4] = {0.f, 0.f, 0.f, 0.f};
    for (int c0 = 0; c0 < HID_; c0 += 32) {
        int cc = c0 + tx;
        int h = cc >> 6, d = cc & 63;
        #pragma unroll
        for (int jj = 0; jj < 4; ++jj) {
            int r = ty + 8 * jj;
            at[r][tx] = ldin_w13(query, (((long)b * H_ + h) * Q_ + q0 + r) * 64 + d, bf);
            wt[r][tx] = ldin_w13(wq, (long)(o0 + r) * HID_ + cc, bf);
        }
        __syncthreads();
        #pragma unroll
        for (int kk = 0; kk < 32; ++kk) {
            float w = wt[tx][kk];
            #pragma unroll
            for (int jj = 0; jj < 4; ++jj)
                acc[jj] += at[ty + 8 * jj][kk] * w;
        }
        __syncthreads();
    }
    #pragma unroll
    for (int jj = 0; jj < 4; ++jj)
        qh[((long)b * Q_ + q0 + ty + 8 * jj) * HID_ + o0 + tx] = 0.125f * acc[jj];
}

// ---------------------------------------------------------------------------
// NEW: hoist the q-independent score reductions:
//   kwmu[b,h,d] = sum_n w_mu[n]*keys[b,n,h*64+d]; kwsg likewise.
// pm(q) = sum_d qh[q,d]*kwmu[d]  — exact reorder of the r6 per-row sum.
// ---------------------------------------------------------------------------
__global__ void kw_w13(const float* __restrict__ keysF,
                       const void* __restrict__ w_mu, const void* __restrict__ w_sg,
                       float* __restrict__ kwmu, float* __restrict__ kwsg,
                       const int* __restrict__ dflag)
{
    const int bf = *dflag;
    const int bh = blockIdx.x;      // b*H + h
    const int b = bh >> 4, h = bh & 15;
    const int d = threadIdx.x;      // 64 threads
    const float* kb = keysF + (long)b * NB_ * HID_ + h * 64 + d;
    float am = 0.f, as = 0.f;
    for (int n = 0; n < NB_; ++n) {
        float kv = kb[(long)n * HID_];
        am += ldin_w13(w_mu, n, bf) * kv;
        as += ldin_w13(w_sg, n, bf) * kv;
    }
    kwmu[(long)bh * 64 + d] = am;
    kwsg[(long)bh * 64 + d] = as;
}

// ---------------------------------------------------------------------------
// NEW attention: 4 waves/block, 4 q-rows per wave (16 rows/block).
// Per row: pm/ps from the hoisted kw vectors (64-length dot + shfl reduce),
// then 512 Gaussians computed ONCE per (row,n) into LDS (8 per lane, not
// 64x-redundant), then cd[j] = sum_n rS[row][n]*V[n,d] with LDS broadcast.
// ctx written in place over this wave's own qh rows (r6-proven pattern).
// ---------------------------------------------------------------------------
__global__ __launch_bounds__(256)
void attn_w13(float* __restrict__ qh, const float* __restrict__ valsF,
              const float* __restrict__ kwmu, const float* __restrict__ kwsg,
              const void* __restrict__ bmu, const void* __restrict__ bsg,
              const int* __restrict__ dflag)
{
    const int bf = *dflag;
    __shared__ float bmuS[512], bvS[512];
    __shared__ float rS[16][512];                       // 32 KB
    const int b = blockIdx.z, h = blockIdx.y;
    const int tid = threadIdx.x, wv = tid >> 6, lane = tid & 63;

    for (int i = tid; i < 512; i += 256) {
        bmuS[i] = ldin_w13(bmu, i, bf);
        float s = ldin_w13(bsg, i, bf);
        bvS[i] = s * s;
    }
    __syncthreads();

    const int q0 = blockIdx.x * 16 + wv * 4;
    const float km = kwmu[((long)b * H_ + h) * 64 + lane];
    const float ks = kwsg[((long)b * H_ + h) * 64 + lane];

    float qv[4], mu[4], sq[4];
    float* qrow[4];
    #pragma unroll
    for (int j = 0; j < 4; ++j) {
        qrow[j] = qh + ((long)b * Q_ + q0 + j) * HID_ + h * 64;
        qv[j] = qrow[j][lane];
        float pm = qv[j] * km, ps = qv[j] * ks;
        #pragma unroll
        for (int off = 32; off > 0; off >>= 1) {
            pm += __shfl_xor(pm, off);
            ps += __shfl_xor(ps, off);
        }
        mu[j] = 1.f / (1.f + expf(-pm));
        float sp = (ps > 0.f) ? (ps + log1pf(expf(-ps))) : log1pf(expf(ps));
        sq[j] = fmaxf(sp, 1e-6f);
    }

    // Gaussians once per (row, n): lane handles n = lane + 64*jj
    #pragma unroll
    for (int j = 0; j < 4; ++j) {
        #pragma unroll
        for (int jj = 0; jj < 8; ++jj) {
            int n = lane + 64 * jj;
            float var = sq[j] + bvS[n];
            float dd = mu[j] - bmuS[n];
            rS[wv * 4 + j][n] = expf(-0.5f * dd * dd / var)
                                / sqrtf(6.283185307179586f * var);
        }
    }
    __syncthreads();   // conservative (rows are wave-private, but cheap)

    const float* vb = valsF + (long)b * NB_ * HID_ + h * 64 + lane;
    float cd[4] = {0.f, 0.f, 0.f, 0.f};
    for (int n = 0; n < 512; ++n) {
        float v = vb[(long)n * HID_];
        #pragma unroll
        for (int j = 0; j < 4; ++j)
            cd[j] += rS[wv * 4 + j][n] * v;      // wave-uniform LDS broadcast
    }
    #pragma unroll
    for (int j = 0; j < 4; ++j)
        qrow[j][lane] = cd[j];                   // in place: own slice only
}

// ---------------------------------------------------------------------------
extern "C" void kernel_launch(void* const* d_in, const int* in_sizes, int n_in,
                              void* d_out, int out_size, void* d_ws, size_t ws_size,
                              hipStream_t stream)
{
    static const int SZ_INS[13] = {16777216,16777216,4194304,2048,1048576,1048576,
                                   1048576,1048576,512,512,1048576,512,512};
    bool mi = (n_in == 13);
    if (mi) for (int i = 0; i < 13; ++i) if (in_sizes[i] != SZ_INS[i]) { mi = false; break; }
    if (!mi) {
        beacon_w13<<<2048, 256, 0, stream>>>((float*)d_out, (long)out_size, 7777777.f);
        return;
    }

    const void* k_in  = d_in[0];
    const void* query = d_in[1];
    const void* wm_f  = d_in[2];
    const void* bmask = d_in[3];
    const void* wq_f  = d_in[4];
    const void* wk_f  = d_in[5];
    const void* wv_f  = d_in[6];
    const void* wo_f  = d_in[7];
    const void* w_mu  = d_in[8];
    const void* w_sg  = d_in[9];
    const void* gs_f  = d_in[10];
    const void* bmu   = d_in[11];
    const void* bsg   = d_in[12];

    char* ws = (char*)d_ws;
    size_t off = 0;
    auto alloc = [&](size_t bytes) { char* p = ws + off; off += (bytes + 255) & ~(size_t)255; return p; };
    int*   dflag = (int*)alloc(256);
    float* kmF   = (float*)alloc((size_t)B_ * HID_ * L_ * 4);   // -> qh -> ctx (in place)
    float* BmatF = (float*)alloc((size_t)B_ * NB_ * HID_ * 4);
    float* keysF = (float*)alloc((size_t)B_ * NB_ * HID_ * 4);
    float* valsF = (float*)alloc((size_t)B_ * NB_ * HID_ * 4);
    float* kwmu  = (float*)alloc((size_t)B_ * H_ * 64 * 4);
    float* kwsg  = (float*)alloc((size_t)B_ * H_ * 64 * 4);
    if (ws_size < off) {
        beacon_w13<<<2048, 256, 0, stream>>>((float*)d_out, (long)out_size, 9999999.f);
        return;
    }
    float* qhF  = kmF;   // kmF dead after sg2
    float* ctxF = kmF;   // attn writes ctx in place over qh

    probe_w13<<<1, 256, 0, stream>>>((const unsigned*)k_in, dflag);

    // G1: masked k (fp32), (B, HID, L)
    sg1_w13<<<dim3(L_ / 32, HID_ / 32, B_), 256, 0, stream>>>(k_in, wm_f, bmask, kmF, dflag);
    // G2: Bmat (B, NB, HID)
    sg2_w13<<<dim3(HID_ / 32, NB_ / 32, B_), 256, 0, stream>>>(kmF, gs_f, BmatF, dflag);
    // G5: qh = 0.125 * qflat @ Wq^T  (overwrites kmF; kmF dead)
    sg5_w13<<<dim3(HID_ / 32, Q_ / 32, B_), 256, 0, stream>>>(query, wq_f, qhF, dflag);
    // G3/G4: keys / vals (B, NB, HID)
    sgw_w13<<<dim3(HID_ / 32, NB_ / 32, B_), 256, 0, stream>>>(
        BmatF, (long)NB_ * HID_, wk_f, keysF, (long)NB_ * HID_, HID_, HID_, 1.f, dflag);
    sgw_w13<<<dim3(HID_ / 32, NB_ / 32, B_), 256, 0, stream>>>(
        BmatF, (long)NB_ * HID_, wv_f, valsF, (long)NB_ * HID_, HID_, HID_, 1.f, dflag);
    // hoisted score reductions
    kw_w13<<<B_ * H_, 64, 0, stream>>>(keysF, w_mu, w_sg, kwmu, kwsg, dflag);
    // attention (ctx in place over qh)
    attn_w13<<<dim3(Q_ / 16, H_, B_), 256, 0, stream>>>(
        qhF, valsF, kwmu, kwsg, bmu, bsg, dflag);
    // G7: out = ctx @ Wo^T  (fp32 to d_out)
    sgw_w13<<<dim3(HID_ / 32, Q_ / 32, B_), 256, 0, stream>>>(
        ctxF, (long)Q_ * HID_, wo_f, (float*)d_out, (long)Q_ * HID_, HID_, HID_, 1.f, dflag);
}

// Round 17
// 5668.362 us; speedup vs baseline: 3.3059x; 1.3490x over previous
//
#include <hip/hip_runtime.h>
#include <hip/hip_bf16.h>

#define L_   2048
#define NB_  512
#define HID_ 1024
#define H_   16
#define D_   64
#define B_   8
#define Q_   2048

typedef unsigned short u16;
typedef float  f32x4  __attribute__((ext_vector_type(4)));
typedef short  short8 __attribute__((ext_vector_type(8)));

__device__ __forceinline__ u16 f2b_z17(float x) {
    __hip_bfloat16 h = __float2bfloat16(x);
    union { __hip_bfloat16 h; u16 u; } cv; cv.h = h; return cv.u;
}
__device__ __forceinline__ float b2f_z17(u16 u) {
    union { u16 u; __hip_bfloat16 h; } cv; cv.u = u; return __bfloat162float(cv.h);
}
__device__ __forceinline__ float ldin_z17(const void* p, long i, int bf) {
    return bf ? b2f_z17(((const u16*)p)[i]) : ((const float*)p)[i];
}

#define GLDSZ17(gp, lp) __builtin_amdgcn_global_load_lds( \
    (const __attribute__((address_space(1))) void*)(gp), \
    (__attribute__((address_space(3))) void*)(lp), 16, 0, 0)

// ---------------------------------------------------------------------------
__global__ void probe_z17(const unsigned* __restrict__ k, int* __restrict__ flag)
{
    __shared__ int cnt;
    if (threadIdx.x == 0) cnt = 0;
    __syncthreads();
    int c = 0;
    for (int i = threadIdx.x; i < 4096; i += 256) {
        unsigned e = (k[i] >> 7) & 0xFFu;
        if (e >= 100u && e <= 135u) c++;
    }
    atomicAdd(&cnt, c);
    __syncthreads();
    if (threadIdx.x == 0) *flag = (cnt > 2048) ? 1 : 0;
}

__global__ void beacon_z17(float* __restrict__ out, long n, float code)
{
    long i = (long)blockIdx.x * blockDim.x + threadIdx.x;
    long st = (long)gridDim.x * blockDim.x;
    for (; i < n; i += st) out[i] = 0.f;
    if (blockIdx.x == 0 && threadIdx.x == 0) out[0] = code;
}

// ---------------------------------------------------------------------------
__global__ void conv_z17(const void* __restrict__ in, u16* __restrict__ out,
                         long n, const int* __restrict__ dflag)
{
    const int bf = *dflag;
    long i = (long)blockIdx.x * blockDim.x + threadIdx.x;
    long st = (long)gridDim.x * blockDim.x;
    for (; i < n; i += st) out[i] = f2b_z17(ldin_z17(in, i, bf));
}

// query (B,H,Q,64) -> qflat (B,Q,HID) bf16
__global__ void qg_z17(const void* __restrict__ q, u16* __restrict__ out,
                       const int* __restrict__ dflag)
{
    const int bf = *dflag;
    const long n = (long)B_ * H_ * Q_ * D_;
    long i = (long)blockIdx.x * blockDim.x + threadIdx.x;
    long st = (long)gridDim.x * blockDim.x;
    for (; i < n; i += st) {
        long dd = i & 63; long t = i >> 6;
        long qq = t & (Q_ - 1); t >>= 11;
        long h = t & (H_ - 1); long b = t >> 4;
        out[(b * Q_ + qq) * HID_ + h * 64 + dd] = f2b_z17(ldin_z17(q, i, bf));
    }
}

// fp32 -> hi + lo residual (bf16)
__global__ void split_z17(const float* __restrict__ in, u16* __restrict__ hi,
                          u16* __restrict__ lo, long n)
{
    long i = (long)blockIdx.x * blockDim.x + threadIdx.x;
    long st = (long)gridDim.x * blockDim.x;
    for (; i < n; i += st) {
        float v = in[i];
        u16 h = f2b_z17(v);
        hi[i] = h;
        lo[i] = f2b_z17(v - b2f_z17(h));
    }
}

// ---------------------------------------------------------------------------
// G1 scalar (r13-proven verbatim)
// ---------------------------------------------------------------------------
__global__ __launch_bounds__(256)
void sg1_z17(const void* __restrict__ k_in, const void* __restrict__ wm,
             const void* __restrict__ bmask, float* __restrict__ kmF,
             const int* __restrict__ dflag)
{
    const int bf = *dflag;
    __shared__ float kt[32][33];
    __shared__ float wt[32][33];
    const int b = blockIdx.z;
    const int m0 = blockIdx.x * 32, c0 = blockIdx.y * 32;
    const int tx = threadIdx.x & 31, ty = threadIdx.x >> 5;
    float acc[4] = {0.f, 0.f, 0.f, 0.f};
    for (int l0 = 0; l0 < L_; l0 += 32) {
        #pragma unroll
        for (int j = 0; j < 4; ++j) {
            int r = ty + 8 * j;
            kt[r][tx] = ldin_z17(k_in, ((long)b * L_ + l0 + r) * HID_ + c0 + tx, bf);
            wt[r][tx] = ldin_z17(wm, (long)(m0 + r) * L_ + l0 + tx, bf);
        }
        __syncthreads();
        #pragma unroll
        for (int kk = 0; kk < 32; ++kk) {
            float w = wt[tx][kk];
            #pragma unroll
            for (int j = 0; j < 4; ++j)
                acc[j] += kt[kk][ty + 8 * j] * w;
        }
        __syncthreads();
    }
    const int m = m0 + tx;
    const float bmv = ldin_z17(bmask, m, bf);
    #pragma unroll
    for (int j = 0; j < 4; ++j) {
        int c = c0 + ty + 8 * j;
        float sg = 1.f / (1.f + expf(-(acc[j] + bmv)));
        float kv = ldin_z17(k_in, ((long)b * L_ + m) * HID_ + c, bf);
        kmF[((long)b * HID_ + c) * L_ + m] = kv * sg;
    }
}

// ---------------------------------------------------------------------------
// G2 scalar (r13-proven verbatim)
// ---------------------------------------------------------------------------
__global__ __launch_bounds__(256)
void sg2_z17(const float* __restrict__ kmF, const void* __restrict__ gs,
             float* __restrict__ BmatF, const int* __restrict__ dflag)
{
    const int bf = *dflag;
    __shared__ float gst[32][33];
    __shared__ float kmt[32][33];
    const int b = blockIdx.z;
    const int c0 = blockIdx.x * 32, n0 = blockIdx.y * 32;
    const int tx = threadIdx.x & 31, ty = threadIdx.x >> 5;
    float acc[4] = {0.f, 0.f, 0.f, 0.f};
    for (int l0 = 0; l0 < L_; l0 += 32) {
        #pragma unroll
        for (int j = 0; j < 4; ++j) {
            int r = ty + 8 * j;
            gst[r][tx] = ldin_z17(gs, (long)(l0 + r) * NB_ + n0 + tx, bf);
            kmt[r][tx] = kmF[((long)b * HID_ + c0 + r) * L_ + l0 + tx];
        }
        __syncthreads();
        #pragma unroll
        for (int kk = 0; kk < 32; ++kk) {
            float km = kmt[tx][kk];
            #pragma unroll
            for (int j = 0; j < 4; ++j)
                acc[j] += gst[kk][ty + 8 * j] * km;
        }
        __syncthreads();
    }
    #pragma unroll
    for (int j = 0; j < 4; ++j)
        BmatF[((long)b * NB_ + n0 + ty + 8 * j) * HID_ + c0 + tx] = acc[j];
}

// ---------------------------------------------------------------------------
// MFMA GEMM (m97 structure): C[M,N] = sum_k A[M,K]*Bt[N,K]
// epi: 3 = fp32 store (scale applied) ; 4 = fp32 accumulate
// NOTE: sA/sB/sC are PER-BATCH element strides (bug in r16 fixed).
// ---------------------------------------------------------------------------
__global__ __launch_bounds__(256)
void gemm_z17(const u16* __restrict__ A, int lda, long sA,
              const u16* __restrict__ Bt, int ldb, long sB,
              float* __restrict__ Cv, int ldc, long sC, int K,
              float scale, int epi)
{
    __shared__ u16 As[128 * 32];
    __shared__ u16 Bs[128 * 32];
    const int tid = threadIdx.x;
    const int wv = tid >> 6, ln = tid & 63;
    const int g = ln >> 4, lr = ln & 15;
    const int wr = wv >> 1, wc = wv & 1;
    const int bm = blockIdx.y * 128, bn = blockIdx.x * 128;
    const u16* Ab = A + (long)blockIdx.z * sA;
    const u16* Bb = Bt + (long)blockIdx.z * sB;

    const int sr = ln >> 2;
    const int scl = (ln & 3) * 8;
    const u16* ga0 = Ab + (long)(bm + wv * 16 + sr) * lda + scl;
    const u16* ga1 = Ab + (long)(bm + (wv + 4) * 16 + sr) * lda + scl;
    const u16* gb0 = Bb + (long)(bn + wv * 16 + sr) * ldb + scl;
    const u16* gb1 = Bb + (long)(bn + (wv + 4) * 16 + sr) * ldb + scl;
    u16* la0 = &As[wv * 512];
    u16* la1 = &As[(wv + 4) * 512];
    u16* lb0 = &Bs[wv * 512];
    u16* lb1 = &Bs[(wv + 4) * 512];

    f32x4 acc[4][4];
    #pragma unroll
    for (int i = 0; i < 4; ++i)
        #pragma unroll
        for (int j = 0; j < 4; ++j) acc[i][j] = (f32x4){0.f, 0.f, 0.f, 0.f};

    for (int k0 = 0; k0 < K; k0 += 32) {
        GLDSZ17(ga0 + k0, la0);
        GLDSZ17(ga1 + k0, la1);
        GLDSZ17(gb0 + k0, lb0);
        GLDSZ17(gb1 + k0, lb1);
        __syncthreads();
        short8 af[4], bfr[4];
        #pragma unroll
        for (int i = 0; i < 4; ++i) af[i] = *(const short8*)&As[(wr * 64 + i * 16 + lr) * 32 + g * 8];
        #pragma unroll
        for (int j = 0; j < 4; ++j) bfr[j] = *(const short8*)&Bs[(wc * 64 + j * 16 + lr) * 32 + g * 8];
        #pragma unroll
        for (int i = 0; i < 4; ++i)
            #pragma unroll
            for (int j = 0; j < 4; ++j)
                acc[i][j] = __builtin_amdgcn_mfma_f32_16x16x32_bf16(af[i], bfr[j], acc[i][j], 0, 0, 0);
        __syncthreads();
    }

    // C/D layout (r4-verified): col = lane&15, row = (lane>>4)*4 + reg
    const int r0 = bm + wr * 64 + g * 4;
    const int c0 = bn + wc * 64 + lr;
    float* C = Cv + (long)blockIdx.z * sC;
    #pragma unroll
    for (int i = 0; i < 4; ++i)
        #pragma unroll
        for (int j = 0; j < 4; ++j)
            #pragma unroll
            for (int r = 0; r < 4; ++r) {
                long o = (long)(r0 + i * 16 + r) * ldc + (c0 + j * 16);
                if (epi == 4) C[o] += acc[i][j][r];
                else          C[o] = scale * acc[i][j][r];
            }
}

// ---------------------------------------------------------------------------
// hoisted score reductions (r13-proven verbatim)
// ---------------------------------------------------------------------------
__global__ void kw_z17(const float* __restrict__ keysF,
                       const void* __restrict__ w_mu, const void* __restrict__ w_sg,
                       float* __restrict__ kwmu, float* __restrict__ kwsg,
                       const int* __restrict__ dflag)
{
    const int bf = *dflag;
    const int bh = blockIdx.x;
    const int b = bh >> 4, h = bh & 15;
    const int d = threadIdx.x;
    const float* kb = keysF + (long)b * NB_ * HID_ + h * 64 + d;
    float am = 0.f, as = 0.f;
    for (int n = 0; n < NB_; ++n) {
        float kv = kb[(long)n * HID_];
        am += ldin_z17(w_mu, n, bf) * kv;
        as += ldin_z17(w_sg, n, bf) * kv;
    }
    kwmu[(long)bh * 64 + d] = am;
    kwsg[(long)bh * 64 + d] = as;
}

// ---------------------------------------------------------------------------
// attention (r13-proven verbatim; fp32 qh in / ctx out in place)
// ---------------------------------------------------------------------------
__global__ __launch_bounds__(256)
void attn_z17(float* __restrict__ qh, const float* __restrict__ valsF,
              const float* __restrict__ kwmu, const float* __restrict__ kwsg,
              const void* __restrict__ bmu, const void* __restrict__ bsg,
              const int* __restrict__ dflag)
{
    const int bf = *dflag;
    __shared__ float bmuS[512], bvS[512];
    __shared__ float rS[16][512];
    const int b = blockIdx.z, h = blockIdx.y;
    const int tid = threadIdx.x, wv = tid >> 6, lane = tid & 63;

    for (int i = tid; i < 512; i += 256) {
        bmuS[i] = ldin_z17(bmu, i, bf);
        float s = ldin_z17(bsg, i, bf);
        bvS[i] = s * s;
    }
    __syncthreads();

    const int q0 = blockIdx.x * 16 + wv * 4;
    const float km = kwmu[((long)b * H_ + h) * 64 + lane];
    const float ks = kwsg[((long)b * H_ + h) * 64 + lane];

    float qv[4], mu[4], sq[4];
    float* qrow[4];
    #pragma unroll
    for (int j = 0; j < 4; ++j) {
        qrow[j] = qh + ((long)b * Q_ + q0 + j) * HID_ + h * 64;
        qv[j] = qrow[j][lane];
        float pm = qv[j] * km, ps = qv[j] * ks;
        #pragma unroll
        for (int off = 32; off > 0; off >>= 1) {
            pm += __shfl_xor(pm, off);
            ps += __shfl_xor(ps, off);
        }
        mu[j] = 1.f / (1.f + expf(-pm));
        float sp = (ps > 0.f) ? (ps + log1pf(expf(-ps))) : log1pf(expf(ps));
        sq[j] = fmaxf(sp, 1e-6f);
    }

    #pragma unroll
    for (int j = 0; j < 4; ++j) {
        #pragma unroll
        for (int jj = 0; jj < 8; ++jj) {
            int n = lane + 64 * jj;
            float var = sq[j] + bvS[n];
            float dd = mu[j] - bmuS[n];
            rS[wv * 4 + j][n] = expf(-0.5f * dd * dd / var)
                                / sqrtf(6.283185307179586f * var);
        }
    }
    __syncthreads();

    const float* vb = valsF + (long)b * NB_ * HID_ + h * 64 + lane;
    float cd[4] = {0.f, 0.f, 0.f, 0.f};
    for (int n = 0; n < 512; ++n) {
        float v = vb[(long)n * HID_];
        #pragma unroll
        for (int j = 0; j < 4; ++j)
            cd[j] += rS[wv * 4 + j][n] * v;
    }
    #pragma unroll
    for (int j = 0; j < 4; ++j)
        qrow[j][lane] = cd[j];
}

// ---------------------------------------------------------------------------
// G7 scalar (r13-proven verbatim)
// ---------------------------------------------------------------------------
__global__ __launch_bounds__(256)
void sgw_z17(const float* __restrict__ A, long Abs, const void* __restrict__ W,
             float* __restrict__ C, long Cbs, int N, int K, float scale,
             const int* __restrict__ dflag)
{
    const int bf = *dflag;
    __shared__ float at[32][33];
    __shared__ float wt[32][33];
    const int b = blockIdx.z;
    const int j0 = blockIdx.x * 32, i0 = blockIdx.y * 32;
    const int tx = threadIdx.x & 31, ty = threadIdx.x >> 5;
    float acc[4] = {0.f, 0.f, 0.f, 0.f};
    const float* Ab = A + (long)b * Abs;
    for (int k0 = 0; k0 < K; k0 += 32) {
        #pragma unroll
        for (int jj = 0; jj < 4; ++jj) {
            int r = ty + 8 * jj;
            at[r][tx] = Ab[(long)(i0 + r) * K + k0 + tx];
            wt[r][tx] = ldin_z17(W, (long)(j0 + r) * K + k0 + tx, bf);
        }
        __syncthreads();
        #pragma unroll
        for (int kk = 0; kk < 32; ++kk) {
            float w = wt[tx][kk];
            #pragma unroll
            for (int jj = 0; jj < 4; ++jj)
                acc[jj] += at[ty + 8 * jj][kk] * w;
        }
        __syncthreads();
    }
    float* Cb = C + (long)b * Cbs;
    #pragma unroll
    for (int jj = 0; jj < 4; ++jj)
        Cb[(long)(i0 + ty + 8 * jj) * N + j0 + tx] = scale * acc[jj];
}

// ---------------------------------------------------------------------------
extern "C" void kernel_launch(void* const* d_in, const int* in_sizes, int n_in,
                              void* d_out, int out_size, void* d_ws, size_t ws_size,
                              hipStream_t stream)
{
    static const int SZ_INS[13] = {16777216,16777216,4194304,2048,1048576,1048576,
                                   1048576,1048576,512,512,1048576,512,512};
    bool mi = (n_in == 13);
    if (mi) for (int i = 0; i < 13; ++i) if (in_sizes[i] != SZ_INS[i]) { mi = false; break; }
    if (!mi) {
        beacon_z17<<<2048, 256, 0, stream>>>((float*)d_out, (long)out_size, 7777777.f);
        return;
    }

    const void* k_in  = d_in[0];
    const void* query = d_in[1];
    const void* wm_f  = d_in[2];
    const void* bmask = d_in[3];
    const void* wq_f  = d_in[4];
    const void* wk_f  = d_in[5];
    const void* wv_f  = d_in[6];
    const void* wo_f  = d_in[7];
    const void* w_mu  = d_in[8];
    const void* w_sg  = d_in[9];
    const void* gs_f  = d_in[10];
    const void* bmu   = d_in[11];
    const void* bsg   = d_in[12];

    char* ws = (char*)d_ws;
    size_t off = 0;
    auto alloc = [&](size_t bytes) { char* p = ws + off; off += (bytes + 255) & ~(size_t)255; return p; };
    const size_t MB = 1024 * 1024;
    const long SBH = (long)NB_ * HID_;       // per-batch stride for NB x HID tensors
    const long SQH = (long)Q_ * HID_;        // per-batch stride for Q x HID tensors
    int*   dflag = (int*)alloc(256);
    char*  RQ    = alloc(64 * MB);           // kmF -> qhF -> ctxF (fp32 B*Q*HID)
    char*  BK    = alloc(16 * MB);           // BmatF -> keysF (fp32 B*NB*HID)
    float* valsF = (float*)alloc(16 * MB);
    u16*   bmh   = (u16*)alloc((size_t)B_ * SBH * 2);     // 8MB
    u16*   bml   = (u16*)alloc((size_t)B_ * SBH * 2);     // 8MB
    u16*   qflat = (u16*)alloc((size_t)B_ * SQH * 2);     // 33.5MB
    u16*   wqc   = (u16*)alloc((size_t)HID_ * HID_ * 2);
    u16*   wkc   = (u16*)alloc((size_t)HID_ * HID_ * 2);
    u16*   wvc   = (u16*)alloc((size_t)HID_ * HID_ * 2);
    float* kwmu  = (float*)alloc((size_t)B_ * H_ * 64 * 4);
    float* kwsg  = (float*)alloc((size_t)B_ * H_ * 64 * 4);
    if (ws_size < off) {
        beacon_z17<<<2048, 256, 0, stream>>>((float*)d_out, (long)out_size, 9999999.f);
        return;
    }
    float* kmF   = (float*)RQ;
    float* qhF   = (float*)RQ;       // overwrites kmF (dead after sg2)
    float* ctxF  = qhF;              // attn writes in place
    float* BmatF = (float*)BK;
    float* keysF = (float*)BK;       // overwrites BmatF (dead after split)

    probe_z17<<<1, 256, 0, stream>>>((const unsigned*)k_in, dflag);
    conv_z17<<<1024, 256, 0, stream>>>(wq_f, wqc, (long)HID_ * HID_, dflag);
    conv_z17<<<1024, 256, 0, stream>>>(wk_f, wkc, (long)HID_ * HID_, dflag);
    conv_z17<<<1024, 256, 0, stream>>>(wv_f, wvc, (long)HID_ * HID_, dflag);

    // G1 (scalar, proven): kmF (B,HID,L) fp32 into RQ
    sg1_z17<<<dim3(L_ / 32, HID_ / 32, B_), 256, 0, stream>>>(k_in, wm_f, bmask, kmF, dflag);
    // G2 (scalar, proven): BmatF (B,NB,HID)
    sg2_z17<<<dim3(HID_ / 32, NB_ / 32, B_), 256, 0, stream>>>(kmF, gs_f, BmatF, dflag);
    // split Bmat -> bmh/bml (BmatF dead after this)
    split_z17<<<2048, 256, 0, stream>>>(BmatF, bmh, bml, (long)B_ * SBH);

    // qflat gather
    qg_z17<<<4096, 256, 0, stream>>>(query, qflat, dflag);
    // G5 (MFMA): qhF = 0.125 * qflat @ Wq^T  (fp32 over RQ; kmF dead)
    gemm_z17<<<dim3(HID_ / 128, Q_ / 128, B_), 256, 0, stream>>>(
        qflat, HID_, SQH, wqc, HID_, 0, qhF, HID_, SQH, HID_, 0.125f, 3);

    // G3 (MFMA 2-pass): keysF = bmh@Wk^T += bml@Wk^T  (into dead BmatF region)
    gemm_z17<<<dim3(HID_ / 128, NB_ / 128, B_), 256, 0, stream>>>(
        bmh, HID_, SBH, wkc, HID_, 0, keysF, HID_, SBH, HID_, 1.f, 3);
    gemm_z17<<<dim3(HID_ / 128, NB_ / 128, B_), 256, 0, stream>>>(
        bml, HID_, SBH, wkc, HID_, 0, keysF, HID_, SBH, HID_, 1.f, 4);
    // hoisted reductions consume keysF
    kw_z17<<<B_ * H_, 64, 0, stream>>>(keysF, w_mu, w_sg, kwmu, kwsg, dflag);

    // G4 (MFMA 2-pass): valsF = bmh@Wv^T += bml@Wv^T
    gemm_z17<<<dim3(HID_ / 128, NB_ / 128, B_), 256, 0, stream>>>(
        bmh, HID_, SBH, wvc, HID_, 0, valsF, HID_, SBH, HID_, 1.f, 3);
    gemm_z17<<<dim3(HID_ / 128, NB_ / 128, B_), 256, 0, stream>>>(
        bml, HID_, SBH, wvc, HID_, 0, valsF, HID_, SBH, HID_, 1.f, 4);

    // attention (proven): ctx in place over qhF
    attn_z17<<<dim3(Q_ / 16, H_, B_), 256, 0, stream>>>(
        qhF, valsF, kwmu, kwsg, bmu, bsg, dflag);

    // G7 (scalar, proven): out = ctx @ Wo^T (fp32 to d_out)
    sgw_z17<<<dim3(HID_ / 32, Q_ / 32, B_), 256, 0, stream>>>(
        ctxF, SQH, wo_f, (float*)d_out, SQH, HID_, HID_, 1.f, dflag);
}

// Round 18
// 2010.437 us; speedup vs baseline: 9.3209x; 2.8195x over previous
//
#include <hip/hip_runtime.h>
#include <hip/hip_bf16.h>

#define L_   2048
#define NB_  512
#define HID_ 1024
#define H_   16
#define D_   64
#define B_   8
#define Q_   2048

typedef unsigned short u16;
typedef float  f32x4  __attribute__((ext_vector_type(4)));
typedef short  short8 __attribute__((ext_vector_type(8)));

__device__ __forceinline__ u16 f2b_a18(float x) {
    __hip_bfloat16 h = __float2bfloat16(x);
    union { __hip_bfloat16 h; u16 u; } cv; cv.h = h; return cv.u;
}
__device__ __forceinline__ float b2f_a18(u16 u) {
    union { u16 u; __hip_bfloat16 h; } cv; cv.u = u; return __bfloat162float(cv.h);
}
__device__ __forceinline__ float ldin_a18(const void* p, long i, int bf) {
    return bf ? b2f_a18(((const u16*)p)[i]) : ((const float*)p)[i];
}

#define GLDSA18(gp, lp) __builtin_amdgcn_global_load_lds( \
    (const __attribute__((address_space(1))) void*)(gp), \
    (__attribute__((address_space(3))) void*)(lp), 16, 0, 0)

// ---------------------------------------------------------------------------
__global__ void probe_a18(const unsigned* __restrict__ k, int* __restrict__ flag)
{
    __shared__ int cnt;
    if (threadIdx.x == 0) cnt = 0;
    __syncthreads();
    int c = 0;
    for (int i = threadIdx.x; i < 4096; i += 256) {
        unsigned e = (k[i] >> 7) & 0xFFu;
        if (e >= 100u && e <= 135u) c++;
    }
    atomicAdd(&cnt, c);
    __syncthreads();
    if (threadIdx.x == 0) *flag = (cnt > 2048) ? 1 : 0;
}

__global__ void beacon_a18(float* __restrict__ out, long n, float code)
{
    long i = (long)blockIdx.x * blockDim.x + threadIdx.x;
    long st = (long)gridDim.x * blockDim.x;
    for (; i < n; i += st) out[i] = 0.f;
    if (blockIdx.x == 0 && threadIdx.x == 0) out[0] = code;
}

// ---------------------------------------------------------------------------
__global__ void conv_a18(const void* __restrict__ in, u16* __restrict__ out,
                         long n, const int* __restrict__ dflag)
{
    const int bf = *dflag;
    long i = (long)blockIdx.x * blockDim.x + threadIdx.x;
    long st = (long)gridDim.x * blockDim.x;
    for (; i < n; i += st) out[i] = f2b_a18(ldin_a18(in, i, bf));
}

// query (B,H,Q,64) -> qflat (B,Q,HID) bf16
__global__ void qg_a18(const void* __restrict__ q, u16* __restrict__ out,
                       const int* __restrict__ dflag)
{
    const int bf = *dflag;
    const long n = (long)B_ * H_ * Q_ * D_;
    long i = (long)blockIdx.x * blockDim.x + threadIdx.x;
    long st = (long)gridDim.x * blockDim.x;
    for (; i < n; i += st) {
        long dd = i & 63; long t = i >> 6;
        long qq = t & (Q_ - 1); t >>= 11;
        long h = t & (H_ - 1); long b = t >> 4;
        out[(b * Q_ + qq) * HID_ + h * 64 + dd] = f2b_a18(ldin_a18(q, i, bf));
    }
}

// fp32 -> hi + lo residual (bf16)   [r17-proven]
__global__ void split_a18(const float* __restrict__ in, u16* __restrict__ hi,
                          u16* __restrict__ lo, long n)
{
    long i = (long)blockIdx.x * blockDim.x + threadIdx.x;
    long st = (long)gridDim.x * blockDim.x;
    for (; i < n; i += st) {
        float v = in[i];
        u16 h = f2b_a18(v);
        hi[i] = h;
        lo[i] = f2b_a18(v - b2f_a18(h));
    }
}

// transpose (r13/r15-lineage proven): in (R,C) -> out (C,R) bf16
__global__ __launch_bounds__(256)
void tr_a18(const void* __restrict__ in, u16* __restrict__ out,
            int R, int C, long sIn, long sOut, const int* __restrict__ dflag)
{
    const int bf = *dflag;
    __shared__ u16 t[64][66];
    const long ibase = (long)blockIdx.z * sIn;
    u16* ob = out + (long)blockIdx.z * sOut;
    const int r0 = blockIdx.y * 64, c0 = blockIdx.x * 64;
    const int lc = threadIdx.x & 63, rb = threadIdx.x >> 6;
    #pragma unroll
    for (int kk = 0; kk < 16; ++kk) {
        int r = rb * 16 + kk;
        t[r][lc] = f2b_a18(ldin_a18(in, ibase + (long)(r0 + r) * C + c0 + lc, bf));
    }
    __syncthreads();
    #pragma unroll
    for (int kk = 0; kk < 16; ++kk) {
        int cr = rb * 16 + kk;
        ob[(long)(c0 + cr) * R + r0 + lc] = t[lc][cr];
    }
}

// elementwise mask epilogue (precise expf, in place over S):
// km[b,c,m] = kT[b,c,m] * sigmoid(S[b,c,m] + bmask[m])
__global__ void ew_a18(float* __restrict__ S, const u16* __restrict__ kT,
                       const void* __restrict__ bmask, const int* __restrict__ dflag)
{
    const int bf = *dflag;
    const long n = (long)B_ * HID_ * L_;
    long i = (long)blockIdx.x * blockDim.x + threadIdx.x;
    long st = (long)gridDim.x * blockDim.x;
    for (; i < n; i += st) {
        long m = i & (L_ - 1);
        float sg = 1.f / (1.f + expf(-(S[i] + ldin_a18(bmask, m, bf))));
        S[i] = b2f_a18(kT[i]) * sg;
    }
}

// ---------------------------------------------------------------------------
// MFMA GEMM (m97 structure, r17-live-proven): C[M,N] = sum_k A[M,K]*Bt[N,K]
// epi: 3 = fp32 store (scale applied) ; 4 = fp32 accumulate
// sA/sB/sC are PER-BATCH element strides.
// ---------------------------------------------------------------------------
__global__ __launch_bounds__(256)
void gemm_a18(const u16* __restrict__ A, int lda, long sA,
              const u16* __restrict__ Bt, int ldb, long sB,
              float* __restrict__ Cv, int ldc, long sC, int K,
              float scale, int epi)
{
    __shared__ u16 As[128 * 32];
    __shared__ u16 Bs[128 * 32];
    const int tid = threadIdx.x;
    const int wv = tid >> 6, ln = tid & 63;
    const int g = ln >> 4, lr = ln & 15;
    const int wr = wv >> 1, wc = wv & 1;
    const int bm = blockIdx.y * 128, bn = blockIdx.x * 128;
    const u16* Ab = A + (long)blockIdx.z * sA;
    const u16* Bb = Bt + (long)blockIdx.z * sB;

    const int sr = ln >> 2;
    const int scl = (ln & 3) * 8;
    const u16* ga0 = Ab + (long)(bm + wv * 16 + sr) * lda + scl;
    const u16* ga1 = Ab + (long)(bm + (wv + 4) * 16 + sr) * lda + scl;
    const u16* gb0 = Bb + (long)(bn + wv * 16 + sr) * ldb + scl;
    const u16* gb1 = Bb + (long)(bn + (wv + 4) * 16 + sr) * ldb + scl;
    u16* la0 = &As[wv * 512];
    u16* la1 = &As[(wv + 4) * 512];
    u16* lb0 = &Bs[wv * 512];
    u16* lb1 = &Bs[(wv + 4) * 512];

    f32x4 acc[4][4];
    #pragma unroll
    for (int i = 0; i < 4; ++i)
        #pragma unroll
        for (int j = 0; j < 4; ++j) acc[i][j] = (f32x4){0.f, 0.f, 0.f, 0.f};

    for (int k0 = 0; k0 < K; k0 += 32) {
        GLDSA18(ga0 + k0, la0);
        GLDSA18(ga1 + k0, la1);
        GLDSA18(gb0 + k0, lb0);
        GLDSA18(gb1 + k0, lb1);
        __syncthreads();
        short8 af[4], bfr[4];
        #pragma unroll
        for (int i = 0; i < 4; ++i) af[i] = *(const short8*)&As[(wr * 64 + i * 16 + lr) * 32 + g * 8];
        #pragma unroll
        for (int j = 0; j < 4; ++j) bfr[j] = *(const short8*)&Bs[(wc * 64 + j * 16 + lr) * 32 + g * 8];
        #pragma unroll
        for (int i = 0; i < 4; ++i)
            #pragma unroll
            for (int j = 0; j < 4; ++j)
                acc[i][j] = __builtin_amdgcn_mfma_f32_16x16x32_bf16(af[i], bfr[j], acc[i][j], 0, 0, 0);
        __syncthreads();
    }

    // C/D layout (r4-verified): col = lane&15, row = (lane>>4)*4 + reg
    const int r0 = bm + wr * 64 + g * 4;
    const int c0 = bn + wc * 64 + lr;
    float* C = Cv + (long)blockIdx.z * sC;
    #pragma unroll
    for (int i = 0; i < 4; ++i)
        #pragma unroll
        for (int j = 0; j < 4; ++j)
            #pragma unroll
            for (int r = 0; r < 4; ++r) {
                long o = (long)(r0 + i * 16 + r) * ldc + (c0 + j * 16);
                if (epi == 4) C[o] += acc[i][j][r];
                else          C[o] = scale * acc[i][j][r];
            }
}

// ---------------------------------------------------------------------------
// G2 scalar (r17-proven verbatim)
// ---------------------------------------------------------------------------
__global__ __launch_bounds__(256)
void sg2_a18(const float* __restrict__ kmF, const void* __restrict__ gs,
             float* __restrict__ BmatF, const int* __restrict__ dflag)
{
    const int bf = *dflag;
    __shared__ float gst[32][33];
    __shared__ float kmt[32][33];
    const int b = blockIdx.z;
    const int c0 = blockIdx.x * 32, n0 = blockIdx.y * 32;
    const int tx = threadIdx.x & 31, ty = threadIdx.x >> 5;
    float acc[4] = {0.f, 0.f, 0.f, 0.f};
    for (int l0 = 0; l0 < L_; l0 += 32) {
        #pragma unroll
        for (int j = 0; j < 4; ++j) {
            int r = ty + 8 * j;
            gst[r][tx] = ldin_a18(gs, (long)(l0 + r) * NB_ + n0 + tx, bf);
            kmt[r][tx] = kmF[((long)b * HID_ + c0 + r) * L_ + l0 + tx];
        }
        __syncthreads();
        #pragma unroll
        for (int kk = 0; kk < 32; ++kk) {
            float km = kmt[tx][kk];
            #pragma unroll
            for (int j = 0; j < 4; ++j)
                acc[j] += gst[kk][ty + 8 * j] * km;
        }
        __syncthreads();
    }
    #pragma unroll
    for (int j = 0; j < 4; ++j)
        BmatF[((long)b * NB_ + n0 + ty + 8 * j) * HID_ + c0 + tx] = acc[j];
}

// ---------------------------------------------------------------------------
// hoisted score reductions (r17-proven verbatim)
// ---------------------------------------------------------------------------
__global__ void kw_a18(const float* __restrict__ keysF,
                       const void* __restrict__ w_mu, const void* __restrict__ w_sg,
                       float* __restrict__ kwmu, float* __restrict__ kwsg,
                       const int* __restrict__ dflag)
{
    const int bf = *dflag;
    const int bh = blockIdx.x;
    const int b = bh >> 4, h = bh & 15;
    const int d = threadIdx.x;
    const float* kb = keysF + (long)b * NB_ * HID_ + h * 64 + d;
    float am = 0.f, as = 0.f;
    for (int n = 0; n < NB_; ++n) {
        float kv = kb[(long)n * HID_];
        am += ldin_a18(w_mu, n, bf) * kv;
        as += ldin_a18(w_sg, n, bf) * kv;
    }
    kwmu[(long)bh * 64 + d] = am;
    kwsg[(long)bh * 64 + d] = as;
}

// ---------------------------------------------------------------------------
// attention (r17-proven verbatim; fp32 qh in / ctx out in place)
// ---------------------------------------------------------------------------
__global__ __launch_bounds__(256)
void attn_a18(float* __restrict__ qh, const float* __restrict__ valsF,
              const float* __restrict__ kwmu, const float* __restrict__ kwsg,
              const void* __restrict__ bmu, const void* __restrict__ bsg,
              const int* __restrict__ dflag)
{
    const int bf = *dflag;
    __shared__ float bmuS[512], bvS[512];
    __shared__ float rS[16][512];
    const int b = blockIdx.z, h = blockIdx.y;
    const int tid = threadIdx.x, wv = tid >> 6, lane = tid & 63;

    for (int i = tid; i < 512; i += 256) {
        bmuS[i] = ldin_a18(bmu, i, bf);
        float s = ldin_a18(bsg, i, bf);
        bvS[i] = s * s;
    }
    __syncthreads();

    const int q0 = blockIdx.x * 16 + wv * 4;
    const float km = kwmu[((long)b * H_ + h) * 64 + lane];
    const float ks = kwsg[((long)b * H_ + h) * 64 + lane];

    float qv[4], mu[4], sq[4];
    float* qrow[4];
    #pragma unroll
    for (int j = 0; j < 4; ++j) {
        qrow[j] = qh + ((long)b * Q_ + q0 + j) * HID_ + h * 64;
        qv[j] = qrow[j][lane];
        float pm = qv[j] * km, ps = qv[j] * ks;
        #pragma unroll
        for (int off = 32; off > 0; off >>= 1) {
            pm += __shfl_xor(pm, off);
            ps += __shfl_xor(ps, off);
        }
        mu[j] = 1.f / (1.f + expf(-pm));
        float sp = (ps > 0.f) ? (ps + log1pf(expf(-ps))) : log1pf(expf(ps));
        sq[j] = fmaxf(sp, 1e-6f);
    }

    #pragma unroll
    for (int j = 0; j < 4; ++j) {
        #pragma unroll
        for (int jj = 0; jj < 8; ++jj) {
            int n = lane + 64 * jj;
            float var = sq[j] + bvS[n];
            float dd = mu[j] - bmuS[n];
            rS[wv * 4 + j][n] = expf(-0.5f * dd * dd / var)
                                / sqrtf(6.283185307179586f * var);
        }
    }
    __syncthreads();

    const float* vb = valsF + (long)b * NB_ * HID_ + h * 64 + lane;
    float cd[4] = {0.f, 0.f, 0.f, 0.f};
    for (int n = 0; n < 512; ++n) {
        float v = vb[(long)n * HID_];
        #pragma unroll
        for (int j = 0; j < 4; ++j)
            cd[j] += rS[wv * 4 + j][n] * v;
    }
    #pragma unroll
    for (int j = 0; j < 4; ++j)
        qrow[j][lane] = cd[j];
}

// ---------------------------------------------------------------------------
extern "C" void kernel_launch(void* const* d_in, const int* in_sizes, int n_in,
                              void* d_out, int out_size, void* d_ws, size_t ws_size,
                              hipStream_t stream)
{
    static const int SZ_INS[13] = {16777216,16777216,4194304,2048,1048576,1048576,
                                   1048576,1048576,512,512,1048576,512,512};
    bool mi = (n_in == 13);
    if (mi) for (int i = 0; i < 13; ++i) if (in_sizes[i] != SZ_INS[i]) { mi = false; break; }
    if (!mi) {
        beacon_a18<<<2048, 256, 0, stream>>>((float*)d_out, (long)out_size, 7777777.f);
        return;
    }

    const void* k_in  = d_in[0];
    const void* query = d_in[1];
    const void* wm_f  = d_in[2];
    const void* bmask = d_in[3];
    const void* wq_f  = d_in[4];
    const void* wk_f  = d_in[5];
    const void* wv_f  = d_in[6];
    const void* wo_f  = d_in[7];
    const void* w_mu  = d_in[8];
    const void* w_sg  = d_in[9];
    const void* gs_f  = d_in[10];
    const void* bmu   = d_in[11];
    const void* bsg   = d_in[12];

    char* ws = (char*)d_ws;
    size_t off = 0;
    auto alloc = [&](size_t bytes) { char* p = ws + off; off += (bytes + 255) & ~(size_t)255; return p; };
    const size_t MiB = 1048576;
    const long SBH = (long)NB_ * HID_;       // per-batch stride, NBxHID
    const long SQH = (long)Q_ * HID_;        // per-batch stride, QxHID
    const long SHL = (long)HID_ * L_;        // per-batch stride, HIDxL
    int*   dflag = (int*)alloc(256);
    char*  RQ    = alloc(64 * MiB);          // wmask[0:8)+kT[8:40) -> qhF/ctxF
    char*  SC    = alloc(64 * MiB);          // scores -> kmF -> qflat[0:32)+bmh/bml[32:48) -> ctxh/ctxl
    char*  BK    = alloc(16 * MiB);          // BmatF -> keysF
    float* valsF = (float*)alloc(16 * MiB);  // vals -> woc (after attn)
    u16*   wqc   = (u16*)alloc((size_t)HID_ * HID_ * 2);
    u16*   wkc   = (u16*)alloc((size_t)HID_ * HID_ * 2);
    u16*   wvc   = (u16*)alloc((size_t)HID_ * HID_ * 2);
    float* kwmu  = (float*)alloc((size_t)B_ * H_ * 64 * 4);
    float* kwsg  = (float*)alloc((size_t)B_ * H_ * 64 * 4);
    if (ws_size < off) {
        beacon_a18<<<2048, 256, 0, stream>>>((float*)d_out, (long)out_size, 9999999.f);
        return;
    }
    u16*   wmask = (u16*)RQ;                     // [0, 8MiB)
    u16*   kTp   = (u16*)(RQ + 8 * MiB);         // [8, 40MiB)
    float* qhF   = (float*)RQ;                   // after G1/ew (wmask,kT dead)
    float* ctxF  = qhF;
    float* SCf   = (float*)SC;                   // scores -> kmF (in place)
    u16*   qflat = (u16*)SC;                     // [0, 32MiB)   after sg2
    u16*   bmh   = (u16*)(SC + 32 * MiB);        // [32, 40MiB)
    u16*   bml   = (u16*)(SC + 40 * MiB);        // [40, 48MiB)
    u16*   ctxh  = (u16*)SC;                     // [0, 32MiB)   after attn
    u16*   ctxl  = (u16*)(SC + 32 * MiB);        // [32, 64MiB)
    float* BmatF = (float*)BK;
    float* keysF = (float*)BK;                   // after split (BmatF dead)
    u16*   woc   = (u16*)valsF;                  // after attn (valsF dead)

    probe_a18<<<1, 256, 0, stream>>>((const unsigned*)k_in, dflag);
    conv_a18<<<1024, 256, 0, stream>>>(wq_f, wqc, (long)HID_ * HID_, dflag);
    conv_a18<<<1024, 256, 0, stream>>>(wk_f, wkc, (long)HID_ * HID_, dflag);
    conv_a18<<<1024, 256, 0, stream>>>(wv_f, wvc, (long)HID_ * HID_, dflag);
    conv_a18<<<2048, 256, 0, stream>>>(wm_f, wmask, (long)L_ * L_, dflag);
    tr_a18<<<dim3(HID_ / 64, L_ / 64, B_), 256, 0, stream>>>(
        k_in, kTp, L_, HID_, (long)L_ * HID_, SHL, dflag);

    // G1a (MFMA, proven epi3): SC = kT @ wmask^T  (fp32 scores)
    gemm_a18<<<dim3(L_ / 128, HID_ / 128, B_), 256, 0, stream>>>(
        kTp, L_, SHL, wmask, L_, 0, SCf, L_, SHL, L_, 1.f, 3);
    // G1b: km = kT * sigmoid(SC + bmask)  (in place, precise expf)
    ew_a18<<<2048, 256, 0, stream>>>(SCf, kTp, bmask, dflag);

    // G2 (scalar, proven): BmatF = Gs^T @ km
    sg2_a18<<<dim3(HID_ / 32, NB_ / 32, B_), 256, 0, stream>>>(SCf, gs_f, BmatF, dflag);
    // split Bmat -> bmh/bml (kmF dead; writes SC[32:48))
    split_a18<<<2048, 256, 0, stream>>>(BmatF, bmh, bml, (long)B_ * SBH);

    // qflat gather into SC[0:32)
    qg_a18<<<4096, 256, 0, stream>>>(query, qflat, dflag);
    // G5 (MFMA, proven): qhF = 0.125 * qflat @ Wq^T  (over RQ; wmask/kT dead)
    gemm_a18<<<dim3(HID_ / 128, Q_ / 128, B_), 256, 0, stream>>>(
        qflat, HID_, SQH, wqc, HID_, 0, qhF, HID_, SQH, HID_, 0.125f, 3);

    // G3 (MFMA 2-pass, proven): keysF = bmh@Wk^T += bml@Wk^T  (over dead BmatF)
    gemm_a18<<<dim3(HID_ / 128, NB_ / 128, B_), 256, 0, stream>>>(
        bmh, HID_, SBH, wkc, HID_, 0, keysF, HID_, SBH, HID_, 1.f, 3);
    gemm_a18<<<dim3(HID_ / 128, NB_ / 128, B_), 256, 0, stream>>>(
        bml, HID_, SBH, wkc, HID_, 0, keysF, HID_, SBH, HID_, 1.f, 4);
    kw_a18<<<B_ * H_, 64, 0, stream>>>(keysF, w_mu, w_sg, kwmu, kwsg, dflag);

    // G4 (MFMA 2-pass, proven): valsF = bmh@Wv^T += bml@Wv^T
    gemm_a18<<<dim3(HID_ / 128, NB_ / 128, B_), 256, 0, stream>>>(
        bmh, HID_, SBH, wvc, HID_, 0, valsF, HID_, SBH, HID_, 1.f, 3);
    gemm_a18<<<dim3(HID_ / 128, NB_ / 128, B_), 256, 0, stream>>>(
        bml, HID_, SBH, wvc, HID_, 0, valsF, HID_, SBH, HID_, 1.f, 4);

    // attention (proven): ctx in place over qhF
    attn_a18<<<dim3(Q_ / 16, H_, B_), 256, 0, stream>>>(
        qhF, valsF, kwmu, kwsg, bmu, bsg, dflag);

    // G7 (MFMA 2-pass, proven constructs): split ctx, then out = ctxh@Wo^T += ctxl@Wo^T
    conv_a18<<<1024, 256, 0, stream>>>(wo_f, woc, (long)HID_ * HID_, dflag);
    split_a18<<<2048, 256, 0, stream>>>(ctxF, ctxh, ctxl, (long)B_ * SQH);
    gemm_a18<<<dim3(HID_ / 128, Q_ / 128, B_), 256, 0, stream>>>(
        ctxh, HID_, SQH, woc, HID_, 0, (float*)d_out, HID_, SQH, HID_, 1.f, 3);
    gemm_a18<<<dim3(HID_ / 128, Q_ / 128, B_), 256, 0, stream>>>(
        ctxl, HID_, SQH, woc, HID_, 0, (float*)d_out, HID_, SQH, HID_, 1.f, 4);
}